// Round 1
// baseline (3230.286 us; speedup 1.0000x reference)
//
#include <hip/hip_runtime.h>

#define NG 64
#define RES 64
#define CH_STRIDE (RES*RES*RES)   // 262144 floats per channel per grid
#define NODES 128
#define LDS_PITCH 132             // 132*4B = 528B rows: 16B-aligned, breaks pow2 banks
#define BLOCK 512

__device__ __forceinline__ float lrelu(float v) {
    return fmaxf(v, 0.2f * v);
}

__global__ __launch_bounds__(BLOCK, 2)
void amgsrn_fused(const float* __restrict__ xs,
                  const float* __restrict__ scales,
                  const float* __restrict__ trans,
                  const float* __restrict__ grids,
                  const float* __restrict__ W0,
                  const float* __restrict__ b0,
                  const float* __restrict__ W1,
                  const float* __restrict__ b1,
                  const float* __restrict__ W2,
                  const float* __restrict__ b2,
                  float* __restrict__ out,
                  int npts)
{
    __shared__ float sW0T[NODES * LDS_PITCH];  // [k][j] = W0[j][k] (transposed)
    __shared__ float sW1 [NODES * LDS_PITCH];  // [j][k] row-major

    const int tid = threadIdx.x;
    for (int i = tid; i < NODES * NODES; i += BLOCK) {
        const int j = i >> 7, k = i & 127;
        sW0T[k * LDS_PITCH + j] = W0[i];
        sW1 [j * LDS_PITCH + k] = W1[i];
    }
    __syncthreads();

    const int n = blockIdx.x * BLOCK + tid;
    if (n >= npts) return;

    const float px = xs[n * 3 + 0];
    const float py = xs[n * 3 + 1];
    const float pz = xs[n * 3 + 2];
    constexpr float INV_SCALE = 1.0f / 1.48f;

    // layer-0 accumulators, filled incrementally as grids are sampled
    float h[NODES];
    #pragma unroll
    for (int j = 0; j < NODES; ++j) h[j] = b0[j];

    for (int g = 0; g < NG; ++g) {
        const float cx = (px * scales[g * 3 + 0] + trans[g * 3 + 0]) * INV_SCALE;
        const float cy = (py * scales[g * 3 + 1] + trans[g * 3 + 1]) * INV_SCALE;
        const float cz = (pz * scales[g * 3 + 2] + trans[g * 3 + 2]) * INV_SCALE;

        // align_corners=True: f = (c+1)*0.5*(RES-1); (c+1)*0.5 exact -> *31.5 identical
        const float fx = (cx + 1.0f) * 31.5f;
        const float fy = (cy + 1.0f) * 31.5f;
        const float fz = (cz + 1.0f) * 31.5f;

        const float fx0 = floorf(fx), fy0 = floorf(fy), fz0 = floorf(fz);
        const float wx = fx - fx0, wy = fy - fy0, wz = fz - fz0;
        const int x0 = (int)fx0, y0 = (int)fy0, z0 = (int)fz0;

        // ---- x axis: one column pair fetched at [xb, xb+1], branchless weights ----
        const int   xb  = min(max(x0, 0), RES - 2);
        const float wx0 = ((unsigned)x0       < (unsigned)RES) ? (1.0f - wx) : 0.0f;
        const float wx1 = ((unsigned)(x0 + 1) < (unsigned)RES) ? wx          : 0.0f;
        // weight landing on position xb (wA) and xb+1 (wB)
        const float wA = (x0 == xb     ? wx0 : 0.0f) + (x0 + 1 == xb ? wx1 : 0.0f);
        const float wB = (x0 == xb + 1 ? wx0 : 0.0f) + (x0 == xb     ? wx1 : 0.0f);

        // ---- y / z axes: masked weights + clamped indices ----
        const float wy0 = ((unsigned)y0       < (unsigned)RES) ? (1.0f - wy) : 0.0f;
        const float wy1 = ((unsigned)(y0 + 1) < (unsigned)RES) ? wy          : 0.0f;
        const int   yc0 = min(max(y0, 0),     RES - 1);
        const int   yc1 = min(max(y0 + 1, 0), RES - 1);

        const float wz0 = ((unsigned)z0       < (unsigned)RES) ? (1.0f - wz) : 0.0f;
        const float wz1 = ((unsigned)(z0 + 1) < (unsigned)RES) ? wz          : 0.0f;
        const int   zc0 = min(max(z0, 0),     RES - 1);
        const int   zc1 = min(max(z0 + 1, 0), RES - 1);

        const float w00 = wz0 * wy0;
        const float w01 = wz0 * wy1;
        const float w10 = wz1 * wy0;
        const float w11 = wz1 * wy1;

        const int o00 = (zc0 * RES + yc0) * RES + xb;
        const int o01 = (zc0 * RES + yc1) * RES + xb;
        const int o10 = (zc1 * RES + yc0) * RES + xb;
        const int o11 = (zc1 * RES + yc1) * RES + xb;

        const float* gp = grids + (size_t)g * (2 * CH_STRIDE);
        const float* gq = gp + CH_STRIDE;

        float f0 = w00 * fmaf(wB, gp[o00 + 1], wA * gp[o00]);
        f0 = fmaf(w01, fmaf(wB, gp[o01 + 1], wA * gp[o01]), f0);
        f0 = fmaf(w10, fmaf(wB, gp[o10 + 1], wA * gp[o10]), f0);
        f0 = fmaf(w11, fmaf(wB, gp[o11 + 1], wA * gp[o11]), f0);

        float f1 = w00 * fmaf(wB, gq[o00 + 1], wA * gq[o00]);
        f1 = fmaf(w01, fmaf(wB, gq[o01 + 1], wA * gq[o01]), f1);
        f1 = fmaf(w10, fmaf(wB, gq[o10 + 1], wA * gq[o10]), f1);
        f1 = fmaf(w11, fmaf(wB, gq[o11 + 1], wA * gq[o11]), f1);

        // ---- layer-0 accumulate: h[j] += f0*W0[j][2g] + f1*W0[j][2g+1] ----
        const float4* rowA = reinterpret_cast<const float4*>(&sW0T[(2 * g)     * LDS_PITCH]);
        const float4* rowB = reinterpret_cast<const float4*>(&sW0T[(2 * g + 1) * LDS_PITCH]);
        #pragma unroll
        for (int q = 0; q < NODES / 4; ++q) {
            const float4 wa = rowA[q];
            const float4 wb = rowB[q];
            h[4 * q + 0] = fmaf(f1, wb.x, fmaf(f0, wa.x, h[4 * q + 0]));
            h[4 * q + 1] = fmaf(f1, wb.y, fmaf(f0, wa.y, h[4 * q + 1]));
            h[4 * q + 2] = fmaf(f1, wb.z, fmaf(f0, wa.z, h[4 * q + 2]));
            h[4 * q + 3] = fmaf(f1, wb.w, fmaf(f0, wa.w, h[4 * q + 3]));
        }
    }

    // lrelu after layer 0
    #pragma unroll
    for (int j = 0; j < NODES; ++j) h[j] = lrelu(h[j]);

    // layer 1 fused with layer 2: h1[j] consumed immediately, never stored
    float oacc = b2[0];
    for (int j = 0; j < NODES; ++j) {
        const float4* row = reinterpret_cast<const float4*>(&sW1[j * LDS_PITCH]);
        float a0 = b1[j], a1 = 0.0f, a2 = 0.0f, a3 = 0.0f;
        #pragma unroll
        for (int q = 0; q < NODES / 4; ++q) {
            const float4 w = row[q];
            a0 = fmaf(h[4 * q + 0], w.x, a0);
            a1 = fmaf(h[4 * q + 1], w.y, a1);
            a2 = fmaf(h[4 * q + 2], w.z, a2);
            a3 = fmaf(h[4 * q + 3], w.w, a3);
        }
        const float s = lrelu((a0 + a1) + (a2 + a3));
        oacc = fmaf(s, W2[j], oacc);
    }
    out[n] = oacc;
}

extern "C" void kernel_launch(void* const* d_in, const int* in_sizes, int n_in,
                              void* d_out, int out_size, void* d_ws, size_t ws_size,
                              hipStream_t stream) {
    const float* xs     = (const float*)d_in[0];
    const float* scales = (const float*)d_in[1];
    const float* trans  = (const float*)d_in[2];
    const float* grids  = (const float*)d_in[3];
    const float* W0     = (const float*)d_in[4];
    const float* b0     = (const float*)d_in[5];
    const float* W1     = (const float*)d_in[6];
    const float* b1     = (const float*)d_in[7];
    const float* W2     = (const float*)d_in[8];
    const float* b2     = (const float*)d_in[9];
    float* out = (float*)d_out;

    const int npts = in_sizes[0] / 3;
    const int nblocks = (npts + BLOCK - 1) / BLOCK;
    amgsrn_fused<<<nblocks, BLOCK, 0, stream>>>(
        xs, scales, trans, grids, W0, b0, W1, b1, W2, b2, out, npts);
}

// Round 2
// 879.273 us; speedup vs baseline: 3.6738x; 3.6738x over previous
//
#include <hip/hip_runtime.h>

#define NG 64
#define RES 64
#define RES3 (RES*RES*RES)        // 262144 cells
#define CH_STRIDE RES3
#define NODES 128
#define LDS_PITCH 132
#define FBLOCK 512                // fused fallback block
#define NBINS 32768               // 32^3

typedef short short8 __attribute__((ext_vector_type(8)));
typedef float f32x16 __attribute__((ext_vector_type(16)));
typedef int   int4v  __attribute__((ext_vector_type(4)));

__device__ __forceinline__ float lrelu(float v) { return fmaxf(v, 0.2f * v); }

__device__ __forceinline__ unsigned bf16rne(float f) {
    unsigned u = __float_as_uint(f);
    return (u + 0x7fffu + ((u >> 16) & 1u)) >> 16;
}

__device__ __forceinline__ int bin_of(float x, float y, float z) {
    int bx = min(max((int)((x + 1.0f) * 16.0f), 0), 31);
    int by = min(max((int)((y + 1.0f) * 16.0f), 0), 31);
    int bz = min(max((int)((z + 1.0f) * 16.0f), 0), 31);
    return (bz << 10) | (by << 5) | bx;   // bx fastest: matches grid x-innermost layout
}

// ---------------------------------------------------------------- sort kernels
__global__ void zero_k(unsigned* cnt) {
    int i = blockIdx.x * blockDim.x + threadIdx.x;
    if (i < NBINS) cnt[i] = 0u;
}

__global__ void hist_k(const float* __restrict__ xs, unsigned* __restrict__ cnt, int npts) {
    int n = blockIdx.x * blockDim.x + threadIdx.x;
    if (n >= npts) return;
    atomicAdd(&cnt[bin_of(xs[n*3], xs[n*3+1], xs[n*3+2])], 1u);
}

__global__ void scan_k(const unsigned* __restrict__ cnt, unsigned* __restrict__ offs) {
    __shared__ unsigned part[1024];
    const int t = threadIdx.x;
    unsigned loc[32]; unsigned run = 0;
    #pragma unroll
    for (int i = 0; i < 32; ++i) { loc[i] = run; run += cnt[t*32 + i]; }
    part[t] = run;
    __syncthreads();
    for (int d = 1; d < 1024; d <<= 1) {
        unsigned v = (t >= d) ? part[t - d] : 0u;
        __syncthreads();
        part[t] += v;
        __syncthreads();
    }
    const unsigned pre = (t > 0) ? part[t-1] : 0u;
    #pragma unroll
    for (int i = 0; i < 32; ++i) offs[t*32 + i] = pre + loc[i];
}

__global__ void scatter_k(const float* __restrict__ xs, unsigned* __restrict__ offs,
                          float* __restrict__ sx, float* __restrict__ sy, float* __restrict__ sz,
                          int* __restrict__ orig, int npts) {
    int n = blockIdx.x * blockDim.x + threadIdx.x;
    if (n >= npts) return;
    float x = xs[n*3], y = xs[n*3+1], z = xs[n*3+2];
    unsigned p = atomicAdd(&offs[bin_of(x, y, z)], 1u);
    sx[p] = x; sy[p] = y; sz[p] = z; orig[p] = n;
}

// ------------------------------------------------------------- grid repack
// wsGrid[(g*RES3 + cell)*2 + c] : channel-interleaved pairs
__global__ void repack_k(const float* __restrict__ g, float* __restrict__ wg, int total) {
    for (int i = blockIdx.x * blockDim.x + threadIdx.x; i < total; i += gridDim.x * blockDim.x) {
        int gi = i >> 18;
        int cell = i & (RES3 - 1);
        const float* base = g + ((size_t)gi << 19);
        wg[(size_t)i*2]   = base[cell];
        wg[(size_t)i*2+1] = base[cell + RES3];
    }
}

// ------------------------------------------------------------- pass 1: gather
template<int PACKED>
__global__ __launch_bounds__(256, 4)
void gather_pass1(const float* __restrict__ sx, const float* __restrict__ sy,
                  const float* __restrict__ sz,
                  const float* __restrict__ grids, const float2* __restrict__ gpk,
                  const float* __restrict__ scales, const float* __restrict__ trans,
                  unsigned* __restrict__ feats, int npts, int npad)
{
    const int s = blockIdx.x * 256 + threadIdx.x;
    if (s >= npts) return;
    const float px = sx[s], py = sy[s], pz = sz[s];
    constexpr float INV_SCALE = 1.0f / 1.48f;

    for (int g = 0; g < NG; ++g) {
        const float cx = (px * scales[g*3+0] + trans[g*3+0]) * INV_SCALE;
        const float cy = (py * scales[g*3+1] + trans[g*3+1]) * INV_SCALE;
        const float cz = (pz * scales[g*3+2] + trans[g*3+2]) * INV_SCALE;

        const float fx = (cx + 1.0f) * 31.5f;
        const float fy = (cy + 1.0f) * 31.5f;
        const float fz = (cz + 1.0f) * 31.5f;

        const float fx0 = floorf(fx), fy0 = floorf(fy), fz0 = floorf(fz);
        const float wx = fx - fx0, wy = fy - fy0, wz = fz - fz0;
        const int x0 = (int)fx0, y0 = (int)fy0, z0 = (int)fz0;

        const int   xb  = min(max(x0, 0), RES - 2);
        const float wx0 = ((unsigned)x0       < (unsigned)RES) ? (1.0f - wx) : 0.0f;
        const float wx1 = ((unsigned)(x0 + 1) < (unsigned)RES) ? wx          : 0.0f;
        const float wA = (x0 == xb     ? wx0 : 0.0f) + (x0 + 1 == xb ? wx1 : 0.0f);
        const float wB = (x0 == xb + 1 ? wx0 : 0.0f) + (x0 == xb     ? wx1 : 0.0f);

        const float wy0 = ((unsigned)y0       < (unsigned)RES) ? (1.0f - wy) : 0.0f;
        const float wy1 = ((unsigned)(y0 + 1) < (unsigned)RES) ? wy          : 0.0f;
        const int   yc0 = min(max(y0, 0),     RES - 1);
        const int   yc1 = min(max(y0 + 1, 0), RES - 1);

        const float wz0 = ((unsigned)z0       < (unsigned)RES) ? (1.0f - wz) : 0.0f;
        const float wz1 = ((unsigned)(z0 + 1) < (unsigned)RES) ? wz          : 0.0f;
        const int   zc0 = min(max(z0, 0),     RES - 1);
        const int   zc1 = min(max(z0 + 1, 0), RES - 1);

        const float w00 = wz0 * wy0, w01 = wz0 * wy1;
        const float w10 = wz1 * wy0, w11 = wz1 * wy1;

        const int o00 = (zc0 * RES + yc0) * RES + xb;
        const int o01 = (zc0 * RES + yc1) * RES + xb;
        const int o10 = (zc1 * RES + yc0) * RES + xb;
        const int o11 = (zc1 * RES + yc1) * RES + xb;

        float f0, f1;
        if constexpr (PACKED) {
            const float2* gp = gpk + ((size_t)g << 18);
            const float2 a00 = gp[o00], c00 = gp[o00 + 1];
            const float2 a01 = gp[o01], c01 = gp[o01 + 1];
            const float2 a10 = gp[o10], c10 = gp[o10 + 1];
            const float2 a11 = gp[o11], c11 = gp[o11 + 1];
            f0 = w00 * fmaf(wB, c00.x, wA * a00.x) + w01 * fmaf(wB, c01.x, wA * a01.x)
               + w10 * fmaf(wB, c10.x, wA * a10.x) + w11 * fmaf(wB, c11.x, wA * a11.x);
            f1 = w00 * fmaf(wB, c00.y, wA * a00.y) + w01 * fmaf(wB, c01.y, wA * a01.y)
               + w10 * fmaf(wB, c10.y, wA * a10.y) + w11 * fmaf(wB, c11.y, wA * a11.y);
        } else {
            const float* gp = grids + (size_t)g * (2 * CH_STRIDE);
            const float* gq = gp + CH_STRIDE;
            f0 = w00 * fmaf(wB, gp[o00+1], wA * gp[o00]) + w01 * fmaf(wB, gp[o01+1], wA * gp[o01])
               + w10 * fmaf(wB, gp[o10+1], wA * gp[o10]) + w11 * fmaf(wB, gp[o11+1], wA * gp[o11]);
            f1 = w00 * fmaf(wB, gq[o00+1], wA * gq[o00]) + w01 * fmaf(wB, gq[o01+1], wA * gq[o01])
               + w10 * fmaf(wB, gq[o10+1], wA * gq[o10]) + w11 * fmaf(wB, gq[o11+1], wA * gq[o11]);
        }
        feats[(size_t)g * npad + s] = bf16rne(f0) | (bf16rne(f1) << 16);
    }
}

// ------------------------------------------------------------- pass 2: MFMA MLP
// block = 256 threads = 4 waves; each block: 256 sorted points.
__device__ __forceinline__ void pack_weights(const float* __restrict__ W,
                                             unsigned (*sB)[4][64][4], int tid) {
    #pragma unroll
    for (int i = 0; i < 8; ++i) {
        const int e = tid + 256 * i;
        const int lane = e & 63, ct = (e >> 6) & 3, ks = e >> 8;
        const int j = ct * 32 + (lane & 31);
        const int k = ks * 16 + (lane >> 5) * 8;
        const float4 f0 = *reinterpret_cast<const float4*>(W + j * 128 + k);
        const float4 f1 = *reinterpret_cast<const float4*>(W + j * 128 + k + 4);
        sB[ks][ct][lane][0] = bf16rne(f0.x) | (bf16rne(f0.y) << 16);
        sB[ks][ct][lane][1] = bf16rne(f0.z) | (bf16rne(f0.w) << 16);
        sB[ks][ct][lane][2] = bf16rne(f1.x) | (bf16rne(f1.y) << 16);
        sB[ks][ct][lane][3] = bf16rne(f1.z) | (bf16rne(f1.w) << 16);
    }
}

__global__ __launch_bounds__(256, 1)
void mlp_pass2(const unsigned* __restrict__ feats,
               const float* __restrict__ W0, const float* __restrict__ b0,
               const float* __restrict__ W1, const float* __restrict__ b1,
               const float* __restrict__ W2, const float* __restrict__ b2,
               const int* __restrict__ orig, float* __restrict__ out,
               int npts, int npad)
{
    __shared__ unsigned sB[8][4][64][4];            // 32 KB packed B-frags
    __shared__ unsigned short sBounce[256][136];    // 69.6 KB transpose bounce

    const int tid = threadIdx.x;
    const int w = tid >> 6, l = tid & 63;
    const int lane31 = l & 31, half = l >> 5;

    pack_weights(W0, sB, tid);

    // prefetch A-frags (feats, packed bf16 pairs; row gp holds k=2gp,2gp+1)
    int4v aF[2][8];
    {
        const size_t colbase = (size_t)blockIdx.x * 256 + w * 64 + lane31;
        #pragma unroll
        for (int rt = 0; rt < 2; ++rt)
            #pragma unroll
            for (int ks = 0; ks < 8; ++ks) {
                const unsigned* p = feats + (size_t)(ks * 8 + half * 4) * npad + colbase + rt * 32;
                aF[rt][ks][0] = (int)p[0];
                aF[rt][ks][1] = (int)p[(size_t)npad];
                aF[rt][ks][2] = (int)p[2 * (size_t)npad];
                aF[rt][ks][3] = (int)p[3 * (size_t)npad];
            }
    }
    __syncthreads();   // sB(W0) ready

    f32x16 acc[2][4];
    #pragma unroll
    for (int rt = 0; rt < 2; ++rt)
        #pragma unroll
        for (int ct = 0; ct < 4; ++ct)
            #pragma unroll
            for (int r = 0; r < 16; ++r) acc[rt][ct][r] = 0.0f;

    // ---- layer 0: h0 = feats @ W0^T ----
    #pragma unroll
    for (int ks = 0; ks < 8; ++ks) {
        short8 bfr[4];
        #pragma unroll
        for (int ct = 0; ct < 4; ++ct)
            bfr[ct] = *reinterpret_cast<const short8*>(&sB[ks][ct][l][0]);
        #pragma unroll
        for (int rt = 0; rt < 2; ++rt) {
            const short8 a = __builtin_bit_cast(short8, aF[rt][ks]);
            #pragma unroll
            for (int ct = 0; ct < 4; ++ct)
                acc[rt][ct] = __builtin_amdgcn_mfma_f32_32x32x16_bf16(a, bfr[ct], acc[rt][ct], 0, 0, 0);
        }
    }
    __syncthreads();   // all waves done reading sB(W0)

    pack_weights(W1, sB, tid);

    float b0v[4];
    #pragma unroll
    for (int ct = 0; ct < 4; ++ct) b0v[ct] = b0[ct * 32 + lane31];

    // epilogue: +b0, lrelu, keep fp32 in acc, write bf16-hi to bounce
    #pragma unroll
    for (int rt = 0; rt < 2; ++rt)
        #pragma unroll
        for (int ct = 0; ct < 4; ++ct)
            #pragma unroll
            for (int r = 0; r < 16; ++r) {
                float h = acc[rt][ct][r] + b0v[ct];
                h = fmaxf(h, 0.2f * h);
                acc[rt][ct][r] = h;
                const int row = w * 64 + rt * 32 + (r & 3) + 8 * (r >> 2) + 4 * half;
                sBounce[row][ct * 32 + lane31] = (unsigned short)bf16rne(h);
            }
    __syncthreads();   // W1 packed + bounce(hi) ready

    f32x16 acc2[2][4];
    #pragma unroll
    for (int rt = 0; rt < 2; ++rt)
        #pragma unroll
        for (int ct = 0; ct < 4; ++ct)
            #pragma unroll
            for (int r = 0; r < 16; ++r) acc2[rt][ct][r] = 0.0f;

    // ---- layer 1, hi part ----
    #pragma unroll
    for (int ks = 0; ks < 8; ++ks) {
        short8 bfr[4];
        #pragma unroll
        for (int ct = 0; ct < 4; ++ct)
            bfr[ct] = *reinterpret_cast<const short8*>(&sB[ks][ct][l][0]);
        #pragma unroll
        for (int rt = 0; rt < 2; ++rt) {
            const int row = w * 64 + rt * 32 + lane31;
            const short8 a = *reinterpret_cast<const short8*>(&sBounce[row][ks * 16 + 8 * half]);
            #pragma unroll
            for (int ct = 0; ct < 4; ++ct)
                acc2[rt][ct] = __builtin_amdgcn_mfma_f32_32x32x16_bf16(a, bfr[ct], acc2[rt][ct], 0, 0, 0);
        }
    }
    __syncthreads();   // done reading bounce(hi)

    // residual (h0 - hi) to bounce, bf16
    #pragma unroll
    for (int rt = 0; rt < 2; ++rt)
        #pragma unroll
        for (int ct = 0; ct < 4; ++ct)
            #pragma unroll
            for (int r = 0; r < 16; ++r) {
                const float h = acc[rt][ct][r];
                const unsigned hb = bf16rne(h);
                const float res = h - __uint_as_float(hb << 16);
                const int row = w * 64 + rt * 32 + (r & 3) + 8 * (r >> 2) + 4 * half;
                sBounce[row][ct * 32 + lane31] = (unsigned short)bf16rne(res);
            }
    __syncthreads();

    // ---- layer 1, residual part ----
    #pragma unroll
    for (int ks = 0; ks < 8; ++ks) {
        short8 bfr[4];
        #pragma unroll
        for (int ct = 0; ct < 4; ++ct)
            bfr[ct] = *reinterpret_cast<const short8*>(&sB[ks][ct][l][0]);
        #pragma unroll
        for (int rt = 0; rt < 2; ++rt) {
            const int row = w * 64 + rt * 32 + lane31;
            const short8 a = *reinterpret_cast<const short8*>(&sBounce[row][ks * 16 + 8 * half]);
            #pragma unroll
            for (int ct = 0; ct < 4; ++ct)
                acc2[rt][ct] = __builtin_amdgcn_mfma_f32_32x32x16_bf16(a, bfr[ct], acc2[rt][ct], 0, 0, 0);
        }
    }

    // ---- layer 2: dot with W2 + cross-lane reduce ----
    float b1v[4], w2v[4];
    #pragma unroll
    for (int ct = 0; ct < 4; ++ct) {
        b1v[ct] = b1[ct * 32 + lane31];
        w2v[ct] = W2[ct * 32 + lane31];
    }
    const float b2v = b2[0];

    #pragma unroll
    for (int rt = 0; rt < 2; ++rt)
        #pragma unroll
        for (int r = 0; r < 16; ++r) {
            float v = 0.0f;
            #pragma unroll
            for (int ct = 0; ct < 4; ++ct) {
                float h1 = acc2[rt][ct][r] + b1v[ct];
                h1 = fmaxf(h1, 0.2f * h1);
                v = fmaf(h1, w2v[ct], v);
            }
            v += __shfl_xor(v, 1);  v += __shfl_xor(v, 2);  v += __shfl_xor(v, 4);
            v += __shfl_xor(v, 8);  v += __shfl_xor(v, 16);
            if (lane31 == 0) {
                const int row = w * 64 + rt * 32 + (r & 3) + 8 * (r >> 2) + 4 * half;
                const long sIdx = (long)blockIdx.x * 256 + row;
                if (sIdx < npts) out[orig[sIdx]] = v + b2v;
            }
        }
}

// ------------------------------------------------------------- fused fallback (round-1)
__global__ __launch_bounds__(FBLOCK, 2)
void amgsrn_fused(const float* __restrict__ xs, const float* __restrict__ scales,
                  const float* __restrict__ trans, const float* __restrict__ grids,
                  const float* __restrict__ W0, const float* __restrict__ b0,
                  const float* __restrict__ W1, const float* __restrict__ b1,
                  const float* __restrict__ W2, const float* __restrict__ b2,
                  float* __restrict__ out, int npts)
{
    __shared__ float sW0T[NODES * LDS_PITCH];
    __shared__ float sW1 [NODES * LDS_PITCH];
    const int tid = threadIdx.x;
    for (int i = tid; i < NODES * NODES; i += FBLOCK) {
        const int j = i >> 7, k = i & 127;
        sW0T[k * LDS_PITCH + j] = W0[i];
        sW1 [j * LDS_PITCH + k] = W1[i];
    }
    __syncthreads();
    const int n = blockIdx.x * FBLOCK + tid;
    if (n >= npts) return;
    const float px = xs[n*3], py = xs[n*3+1], pz = xs[n*3+2];
    constexpr float INV_SCALE = 1.0f / 1.48f;
    float h[NODES];
    #pragma unroll
    for (int j = 0; j < NODES; ++j) h[j] = b0[j];
    for (int g = 0; g < NG; ++g) {
        const float cx = (px * scales[g*3+0] + trans[g*3+0]) * INV_SCALE;
        const float cy = (py * scales[g*3+1] + trans[g*3+1]) * INV_SCALE;
        const float cz = (pz * scales[g*3+2] + trans[g*3+2]) * INV_SCALE;
        const float fx = (cx + 1.0f) * 31.5f, fy = (cy + 1.0f) * 31.5f, fz = (cz + 1.0f) * 31.5f;
        const float fx0 = floorf(fx), fy0 = floorf(fy), fz0 = floorf(fz);
        const float wx = fx - fx0, wy = fy - fy0, wz = fz - fz0;
        const int x0 = (int)fx0, y0 = (int)fy0, z0 = (int)fz0;
        const int xb = min(max(x0, 0), RES - 2);
        const float wx0 = ((unsigned)x0 < (unsigned)RES) ? (1.0f - wx) : 0.0f;
        const float wx1 = ((unsigned)(x0+1) < (unsigned)RES) ? wx : 0.0f;
        const float wA = (x0 == xb ? wx0 : 0.0f) + (x0 + 1 == xb ? wx1 : 0.0f);
        const float wB = (x0 == xb + 1 ? wx0 : 0.0f) + (x0 == xb ? wx1 : 0.0f);
        const float wy0 = ((unsigned)y0 < (unsigned)RES) ? (1.0f - wy) : 0.0f;
        const float wy1 = ((unsigned)(y0+1) < (unsigned)RES) ? wy : 0.0f;
        const int yc0 = min(max(y0, 0), RES-1), yc1 = min(max(y0+1, 0), RES-1);
        const float wz0 = ((unsigned)z0 < (unsigned)RES) ? (1.0f - wz) : 0.0f;
        const float wz1 = ((unsigned)(z0+1) < (unsigned)RES) ? wz : 0.0f;
        const int zc0 = min(max(z0, 0), RES-1), zc1 = min(max(z0+1, 0), RES-1);
        const float w00 = wz0*wy0, w01 = wz0*wy1, w10 = wz1*wy0, w11 = wz1*wy1;
        const int o00 = (zc0*RES+yc0)*RES+xb, o01 = (zc0*RES+yc1)*RES+xb;
        const int o10 = (zc1*RES+yc0)*RES+xb, o11 = (zc1*RES+yc1)*RES+xb;
        const float* gp = grids + (size_t)g * (2*CH_STRIDE);
        const float* gq = gp + CH_STRIDE;
        float f0 = w00*fmaf(wB, gp[o00+1], wA*gp[o00]);
        f0 = fmaf(w01, fmaf(wB, gp[o01+1], wA*gp[o01]), f0);
        f0 = fmaf(w10, fmaf(wB, gp[o10+1], wA*gp[o10]), f0);
        f0 = fmaf(w11, fmaf(wB, gp[o11+1], wA*gp[o11]), f0);
        float f1 = w00*fmaf(wB, gq[o00+1], wA*gq[o00]);
        f1 = fmaf(w01, fmaf(wB, gq[o01+1], wA*gq[o01]), f1);
        f1 = fmaf(w10, fmaf(wB, gq[o10+1], wA*gq[o10]), f1);
        f1 = fmaf(w11, fmaf(wB, gq[o11+1], wA*gq[o11]), f1);
        const float4* rowA = reinterpret_cast<const float4*>(&sW0T[(2*g) * LDS_PITCH]);
        const float4* rowB = reinterpret_cast<const float4*>(&sW0T[(2*g+1) * LDS_PITCH]);
        #pragma unroll
        for (int q = 0; q < NODES/4; ++q) {
            const float4 wa = rowA[q], wb = rowB[q];
            h[4*q+0] = fmaf(f1, wb.x, fmaf(f0, wa.x, h[4*q+0]));
            h[4*q+1] = fmaf(f1, wb.y, fmaf(f0, wa.y, h[4*q+1]));
            h[4*q+2] = fmaf(f1, wb.z, fmaf(f0, wa.z, h[4*q+2]));
            h[4*q+3] = fmaf(f1, wb.w, fmaf(f0, wa.w, h[4*q+3]));
        }
    }
    #pragma unroll
    for (int j = 0; j < NODES; ++j) h[j] = lrelu(h[j]);
    float oacc = b2[0];
    for (int j = 0; j < NODES; ++j) {
        const float4* row = reinterpret_cast<const float4*>(&sW1[j * LDS_PITCH]);
        float a0 = b1[j], a1 = 0.0f, a2 = 0.0f, a3 = 0.0f;
        #pragma unroll
        for (int q = 0; q < NODES/4; ++q) {
            const float4 wv = row[q];
            a0 = fmaf(h[4*q+0], wv.x, a0);
            a1 = fmaf(h[4*q+1], wv.y, a1);
            a2 = fmaf(h[4*q+2], wv.z, a2);
            a3 = fmaf(h[4*q+3], wv.w, a3);
        }
        const float sv = lrelu((a0 + a1) + (a2 + a3));
        oacc = fmaf(sv, W2[j], oacc);
    }
    out[n] = oacc;
}

// ---------------------------------------------------------------- launcher
extern "C" void kernel_launch(void* const* d_in, const int* in_sizes, int n_in,
                              void* d_out, int out_size, void* d_ws, size_t ws_size,
                              hipStream_t stream) {
    const float* xs     = (const float*)d_in[0];
    const float* scales = (const float*)d_in[1];
    const float* trans  = (const float*)d_in[2];
    const float* grids  = (const float*)d_in[3];
    const float* W0     = (const float*)d_in[4];
    const float* b0     = (const float*)d_in[5];
    const float* W1     = (const float*)d_in[6];
    const float* b1     = (const float*)d_in[7];
    const float* W2     = (const float*)d_in[8];
    const float* b2     = (const float*)d_in[9];
    float* out = (float*)d_out;

    const int npts = in_sizes[0] / 3;
    const int npad = (npts + 255) & ~255;

    // ws layout (256B-aligned)
    auto al = [](size_t v) { return (v + 255) & ~(size_t)255; };
    size_t off = 0;
    const size_t featsOff = off; off += al((size_t)64 * npad * 4);
    const size_t sxOff    = off; off += al((size_t)npad * 4);
    const size_t syOff    = off; off += al((size_t)npad * 4);
    const size_t szOff    = off; off += al((size_t)npad * 4);
    const size_t origOff  = off; off += al((size_t)npad * 4);
    const size_t cntOff   = off; off += al((size_t)NBINS * 4);
    const size_t offsOff  = off; off += al((size_t)NBINS * 4);
    const size_t needNoPack = off;
    const size_t gridOff  = off; off += al((size_t)NG * RES3 * 2 * 4);
    const size_t needPack = off;

    const int nb = (npts + 255) / 256;

    if (ws_size < needNoPack) {
        // fallback: round-1 fused kernel
        const int fb = (npts + FBLOCK - 1) / FBLOCK;
        amgsrn_fused<<<fb, FBLOCK, 0, stream>>>(xs, scales, trans, grids,
                                                W0, b0, W1, b1, W2, b2, out, npts);
        return;
    }

    char* ws = (char*)d_ws;
    unsigned* feats = (unsigned*)(ws + featsOff);
    float* sx = (float*)(ws + sxOff);
    float* sy = (float*)(ws + syOff);
    float* sz = (float*)(ws + szOff);
    int*   orig = (int*)(ws + origOff);
    unsigned* cnt  = (unsigned*)(ws + cntOff);
    unsigned* offs = (unsigned*)(ws + offsOff);
    float* wsGrid = (float*)(ws + gridOff);
    const bool packed = (ws_size >= needPack);

    zero_k<<<(NBINS + 255) / 256, 256, 0, stream>>>(cnt);
    if (packed)
        repack_k<<<4096, 256, 0, stream>>>(grids, wsGrid, NG * RES3);
    hist_k<<<nb, 256, 0, stream>>>(xs, cnt, npts);
    scan_k<<<1, 1024, 0, stream>>>(cnt, offs);
    scatter_k<<<nb, 256, 0, stream>>>(xs, offs, sx, sy, sz, orig, npts);

    if (packed)
        gather_pass1<1><<<nb, 256, 0, stream>>>(sx, sy, sz, grids, (const float2*)wsGrid,
                                                scales, trans, feats, npts, npad);
    else
        gather_pass1<0><<<nb, 256, 0, stream>>>(sx, sy, sz, grids, nullptr,
                                                scales, trans, feats, npts, npad);

    mlp_pass2<<<npad / 256, 256, 0, stream>>>(feats, W0, b0, W1, b1, W2, b2,
                                              orig, out, npts, npad);
}

// Round 3
// 638.350 us; speedup vs baseline: 5.0604x; 1.3774x over previous
//
#include <hip/hip_runtime.h>

#define NG 64
#define RES 64
#define RES3 (RES*RES*RES)
#define NODES 128
#define NBINS 32768
#define FBLOCK 512
#define LDS_PITCH 132

typedef short    short8 __attribute__((ext_vector_type(8)));
typedef float    f32x16 __attribute__((ext_vector_type(16)));
typedef unsigned uint4v __attribute__((ext_vector_type(4)));

__device__ __forceinline__ float lrelu(float v) { return fmaxf(v, 0.2f * v); }

__device__ __forceinline__ unsigned cvtpk(float lo, float hi) {
    unsigned r;
    asm("v_cvt_pk_bf16_f32 %0, %1, %2" : "=v"(r) : "v"(lo), "v"(hi));
    return r;
}

// permlane32_swap: new_x[32:63] = old_y[0:31]; new_y[0:31] = old_x[32:63]
__device__ __forceinline__ void swap32(unsigned &x, unsigned &y) {
    auto rr = __builtin_amdgcn_permlane32_swap(x, y, false, false);
    x = rr[0]; y = rr[1];
}

__device__ __forceinline__ int bin_of(float x, float y, float z) {
    int bx = min(max((int)((x + 1.0f) * 16.0f), 0), 31);
    int by = min(max((int)((y + 1.0f) * 16.0f), 0), 31);
    int bz = min(max((int)((z + 1.0f) * 16.0f), 0), 31);
    return (bz << 10) | (by << 5) | bx;
}

// ---------------------------------------------------------------- sort
__global__ void zero_k(unsigned* cnt) {
    int i = blockIdx.x * blockDim.x + threadIdx.x;
    if (i < NBINS) cnt[i] = 0u;
}

__global__ void hist_k(const float* __restrict__ xs, unsigned* __restrict__ cnt, int npts) {
    int n = blockIdx.x * blockDim.x + threadIdx.x;
    if (n >= npts) return;
    atomicAdd(&cnt[bin_of(xs[n*3], xs[n*3+1], xs[n*3+2])], 1u);
}

__global__ void scan_k(const unsigned* __restrict__ cnt, unsigned* __restrict__ offs) {
    __shared__ unsigned part[1024];
    const int t = threadIdx.x;
    unsigned loc[32]; unsigned run = 0;
    #pragma unroll
    for (int i = 0; i < 32; ++i) { loc[i] = run; run += cnt[t*32 + i]; }
    part[t] = run;
    __syncthreads();
    for (int d = 1; d < 1024; d <<= 1) {
        unsigned v = (t >= d) ? part[t - d] : 0u;
        __syncthreads();
        part[t] += v;
        __syncthreads();
    }
    const unsigned pre = (t > 0) ? part[t-1] : 0u;
    #pragma unroll
    for (int i = 0; i < 32; ++i) offs[t*32 + i] = pre + loc[i];
}

__global__ void scatter_k(const float* __restrict__ xs, unsigned* __restrict__ offs,
                          float4* __restrict__ sp, int npts) {
    int n = blockIdx.x * blockDim.x + threadIdx.x;
    if (n >= npts) return;
    float x = xs[n*3], y = xs[n*3+1], z = xs[n*3+2];
    unsigned p = atomicAdd(&offs[bin_of(x, y, z)], 1u);
    sp[p] = make_float4(x, y, z, __int_as_float(n));
}

// ---------------------------------------------------------------- grid repack (channel-interleaved)
__global__ void repack_k(const float* __restrict__ g, float2* __restrict__ wg, int total) {
    for (int i = blockIdx.x * blockDim.x + threadIdx.x; i < total; i += gridDim.x * blockDim.x) {
        int gi = i >> 18, cell = i & (RES3 - 1);
        const float* base = g + ((size_t)gi << 19);
        wg[i] = make_float2(base[cell], base[cell + RES3]);
    }
}

// ---------------------------------------------------------------- weight/bias/coef pre-pack
// A-frag layout (32x32x16 bf16): u32 idx = ((jt*8+s)*64+l)*4+q
//   row j = 32*jt + (l&31);  k = 16*s + (l>>5)*8 + 2q (+1 in hi half)
// bias/W2 layout (D^T): idx = jt*32 + h*16 + r  ->  feature 32jt + (r&3)+8(r>>2)+4h
__global__ void packw_k(const float* __restrict__ W0, const float* __restrict__ W1,
                        const float* __restrict__ b0, const float* __restrict__ b1,
                        const float* __restrict__ W2,
                        const float* __restrict__ scales, const float* __restrict__ trans,
                        unsigned* __restrict__ wp0, unsigned* __restrict__ wp1,
                        float* __restrict__ b0p, float* __restrict__ b1p, float* __restrict__ w2p,
                        float4* __restrict__ coefA, float4* __restrict__ coefB)
{
    const int i = blockIdx.x * 256 + threadIdx.x;
    if (i < 8192) {
        const int q = i & 3, l = (i >> 2) & 63, s = (i >> 8) & 7, jt = i >> 11;
        const int j  = jt * 32 + (l & 31);
        const int k0 = s * 16 + (l >> 5) * 8 + q * 2;
        wp0[i] = cvtpk(W0[j*128 + k0], W0[j*128 + k0 + 1]);
        wp1[i] = cvtpk(W1[j*128 + k0], W1[j*128 + k0 + 1]);
    } else if (i < 8320) {
        const int t = i - 8192;
        const int r = t & 15, h = (t >> 4) & 1, jt = t >> 5;
        const int f = 32*jt + (r & 3) + 8*(r >> 2) + 4*h;
        b0p[t] = b0[f]; b1p[t] = b1[f]; w2p[t] = W2[f];
    } else if (i < 8384) {
        const int g = i - 8320;
        constexpr float K = 31.5f / 1.48f;
        coefA[g] = make_float4(scales[g*3+0]*K, scales[g*3+1]*K, scales[g*3+2]*K, 0.0f);
        coefB[g] = make_float4(fmaf(trans[g*3+0], K, 31.5f),
                               fmaf(trans[g*3+1], K, 31.5f),
                               fmaf(trans[g*3+2], K, 31.5f), 0.0f);
    }
}

// ---------------------------------------------------------------- fused gather + MLP (no LDS, no barriers)
template<int PACKED>
__global__ __launch_bounds__(256, 2)
void fused_k(const float4* __restrict__ sp,
             const float2* __restrict__ gpk,
             const float*  __restrict__ grids,
             const float4* __restrict__ coefA,
             const float4* __restrict__ coefB,
             const uint4v* __restrict__ wp0,
             const uint4v* __restrict__ wp1,
             const float*  __restrict__ b0p,
             const float*  __restrict__ b1p,
             const float*  __restrict__ w2p,
             const float*  __restrict__ b2,
             float* __restrict__ out, int npts)
{
    const int tid  = threadIdx.x;
    const int l    = tid & 63;
    const int half = l >> 5;
    const int sidx = blockIdx.x * 256 + tid;
    const float4 P = sp[min(sidx, npts - 1)];
    const float px = P.x, py = P.y, pz = P.z;

    // layer-0 accumulators (D^T), bias folded into C-init
    f32x16 acc[4][2];
    #pragma unroll
    for (int jt = 0; jt < 4; ++jt)
        #pragma unroll
        for (int q4 = 0; q4 < 4; ++q4) {
            const float4 bv = *reinterpret_cast<const float4*>(b0p + jt*32 + half*16 + q4*4);
            #pragma unroll
            for (int c = 0; c < 4; ++c) {
                const float v = ((const float*)&bv)[c];
                acc[jt][0][q4*4+c] = v;
                acc[jt][1][q4*4+c] = v;
            }
        }

    // gather 8 grids per slice -> permlane transpose -> layer-0 MFMAs
    #pragma unroll 2
    for (int s = 0; s < 8; ++s) {
        unsigned f8[8];
        #pragma unroll
        for (int gi = 0; gi < 8; ++gi) {
            const int g = s*8 + gi;
            const float4 cA = coefA[g];
            const float4 cB = coefB[g];
            const float fx = fmaf(px, cA.x, cB.x);
            const float fy = fmaf(py, cA.y, cB.y);
            const float fz = fmaf(pz, cA.z, cB.z);
            const float fx0 = floorf(fx), fy0 = floorf(fy), fz0 = floorf(fz);
            const float wx = fx - fx0, wy = fy - fy0, wz = fz - fz0;
            const int x0 = (int)fx0, y0 = (int)fy0, z0 = (int)fz0;

            const int   xb  = min(max(x0, 0), RES - 2);
            const float wx0 = ((unsigned)x0       < (unsigned)RES) ? (1.0f - wx) : 0.0f;
            const float wx1 = ((unsigned)(x0 + 1) < (unsigned)RES) ? wx          : 0.0f;
            const float wA = (x0 == xb     ? wx0 : 0.0f) + (x0 + 1 == xb ? wx1 : 0.0f);
            const float wB = (x0 == xb + 1 ? wx0 : 0.0f) + (x0 == xb     ? wx1 : 0.0f);

            const float wy0 = ((unsigned)y0       < (unsigned)RES) ? (1.0f - wy) : 0.0f;
            const float wy1 = ((unsigned)(y0 + 1) < (unsigned)RES) ? wy          : 0.0f;
            const int yc0 = min(max(y0, 0), RES-1), yc1 = min(max(y0+1, 0), RES-1);

            const float wz0 = ((unsigned)z0       < (unsigned)RES) ? (1.0f - wz) : 0.0f;
            const float wz1 = ((unsigned)(z0 + 1) < (unsigned)RES) ? wz          : 0.0f;
            const int zc0 = min(max(z0, 0), RES-1), zc1 = min(max(z0+1, 0), RES-1);

            const float w00 = wz0*wy0, w01 = wz0*wy1, w10 = wz1*wy0, w11 = wz1*wy1;
            const int o00 = (zc0*RES + yc0)*RES + xb;
            const int o01 = (zc0*RES + yc1)*RES + xb;
            const int o10 = (zc1*RES + yc0)*RES + xb;
            const int o11 = (zc1*RES + yc1)*RES + xb;

            float f0, f1;
            if constexpr (PACKED) {
                const float2* gp = gpk + ((size_t)g << 18);
                const float2 a00 = gp[o00], c00 = gp[o00+1];
                const float2 a01 = gp[o01], c01 = gp[o01+1];
                const float2 a10 = gp[o10], c10 = gp[o10+1];
                const float2 a11 = gp[o11], c11 = gp[o11+1];
                f0 = w00*fmaf(wB,c00.x,wA*a00.x) + w01*fmaf(wB,c01.x,wA*a01.x)
                   + w10*fmaf(wB,c10.x,wA*a10.x) + w11*fmaf(wB,c11.x,wA*a11.x);
                f1 = w00*fmaf(wB,c00.y,wA*a00.y) + w01*fmaf(wB,c01.y,wA*a01.y)
                   + w10*fmaf(wB,c10.y,wA*a10.y) + w11*fmaf(wB,c11.y,wA*a11.y);
            } else {
                const float* gp = grids + (size_t)g * (2*RES3);
                const float* gq = gp + RES3;
                f0 = w00*fmaf(wB,gp[o00+1],wA*gp[o00]) + w01*fmaf(wB,gp[o01+1],wA*gp[o01])
                   + w10*fmaf(wB,gp[o10+1],wA*gp[o10]) + w11*fmaf(wB,gp[o11+1],wA*gp[o11]);
                f1 = w00*fmaf(wB,gq[o00+1],wA*gq[o00]) + w01*fmaf(wB,gq[o01+1],wA*gq[o01])
                   + w10*fmaf(wB,gq[o10+1],wA*gq[o10]) + w11*fmaf(wB,gq[o11+1],wA*gq[o11]);
            }
            f8[gi] = cvtpk(f0, f1);   // k=2g -> lo, k=2g+1 -> hi
        }

        // B-frag build: pt0 = f8[0..3], pt1 = f8[4..7] after half-exchange
        #pragma unroll
        for (int q = 0; q < 4; ++q) swap32(f8[q], f8[4+q]);
        const short8 bf0 = __builtin_bit_cast(short8, (uint4v){f8[0], f8[1], f8[2], f8[3]});
        const short8 bf1 = __builtin_bit_cast(short8, (uint4v){f8[4], f8[5], f8[6], f8[7]});

        #pragma unroll
        for (int jt = 0; jt < 4; ++jt) {
            const short8 wa = __builtin_bit_cast(short8, wp0[(jt*8 + s)*64 + l]);
            acc[jt][0] = __builtin_amdgcn_mfma_f32_32x32x16_bf16(wa, bf0, acc[jt][0], 0, 0, 0);
            acc[jt][1] = __builtin_amdgcn_mfma_f32_32x32x16_bf16(wa, bf1, acc[jt][1], 0, 0, 0);
        }
    }

    // activation + hi/res bf16 split (packed), per-tile so acc dies incrementally
    unsigned pkh[2][32], pkr[2][32];
    #pragma unroll
    for (int jt = 0; jt < 4; ++jt)
        #pragma unroll
        for (int pt = 0; pt < 2; ++pt)
            #pragma unroll
            for (int q = 0; q < 8; ++q) {
                float v0 = lrelu(acc[jt][pt][2*q]);
                float v1 = lrelu(acc[jt][pt][2*q+1]);
                const unsigned ph = cvtpk(v0, v1);
                const float r0 = v0 - __uint_as_float(ph << 16);
                const float r1 = v1 - __uint_as_float(ph & 0xffff0000u);
                pkh[pt][jt*8 + q] = ph;
                pkr[pt][jt*8 + q] = cvtpk(r0, r1);
            }
    // in-place permlane transpose into layer-1 B-frag layout: frag(s) = pk[4s..4s+3]
    #pragma unroll
    for (int pt = 0; pt < 2; ++pt)
        #pragma unroll
        for (int s = 0; s < 8; ++s)
            #pragma unroll
            for (int i = 0; i < 2; ++i) {
                swap32(pkh[pt][4*s + i], pkh[pt][4*s + i + 2]);
                swap32(pkr[pt][4*s + i], pkr[pt][4*s + i + 2]);
            }

    // layer 1 (hi + residual MFMAs) fused with layer 2 dot
    float psum0 = 0.0f, psum1 = 0.0f;
    #pragma unroll
    for (int jt2 = 0; jt2 < 4; ++jt2) {
        f32x16 a2[2];
        #pragma unroll
        for (int q4 = 0; q4 < 4; ++q4) {
            const float4 bv = *reinterpret_cast<const float4*>(b1p + jt2*32 + half*16 + q4*4);
            #pragma unroll
            for (int c = 0; c < 4; ++c) {
                const float v = ((const float*)&bv)[c];
                a2[0][q4*4+c] = v;
                a2[1][q4*4+c] = v;
            }
        }
        #pragma unroll
        for (int s = 0; s < 8; ++s) {
            const short8 wa = __builtin_bit_cast(short8, wp1[(jt2*8 + s)*64 + l]);
            #pragma unroll
            for (int pt = 0; pt < 2; ++pt) {
                const short8 bh = __builtin_bit_cast(short8,
                    (uint4v){pkh[pt][4*s], pkh[pt][4*s+1], pkh[pt][4*s+2], pkh[pt][4*s+3]});
                const short8 br = __builtin_bit_cast(short8,
                    (uint4v){pkr[pt][4*s], pkr[pt][4*s+1], pkr[pt][4*s+2], pkr[pt][4*s+3]});
                a2[pt] = __builtin_amdgcn_mfma_f32_32x32x16_bf16(wa, bh, a2[pt], 0, 0, 0);
                a2[pt] = __builtin_amdgcn_mfma_f32_32x32x16_bf16(wa, br, a2[pt], 0, 0, 0);
            }
        }
        #pragma unroll
        for (int q4 = 0; q4 < 4; ++q4) {
            const float4 wv = *reinterpret_cast<const float4*>(w2p + jt2*32 + half*16 + q4*4);
            #pragma unroll
            for (int c = 0; c < 4; ++c) {
                const float wc = ((const float*)&wv)[c];
                psum0 = fmaf(lrelu(a2[0][q4*4+c]), wc, psum0);
                psum1 = fmaf(lrelu(a2[1][q4*4+c]), wc, psum1);
            }
        }
    }

    const float t0 = psum0 + __shfl_xor(psum0, 32);
    const float t1 = psum1 + __shfl_xor(psum1, 32);
    const float val = (half == 0 ? t0 : t1) + b2[0];
    if (sidx < npts) out[__float_as_int(P.w)] = val;
}

// ---------------------------------------------------------------- round-1 fused fallback
__global__ __launch_bounds__(FBLOCK, 2)
void amgsrn_fused(const float* __restrict__ xs, const float* __restrict__ scales,
                  const float* __restrict__ trans, const float* __restrict__ grids,
                  const float* __restrict__ W0, const float* __restrict__ b0,
                  const float* __restrict__ W1, const float* __restrict__ b1,
                  const float* __restrict__ W2, const float* __restrict__ b2,
                  float* __restrict__ out, int npts)
{
    __shared__ float sW0T[NODES * LDS_PITCH];
    __shared__ float sW1 [NODES * LDS_PITCH];
    const int tid = threadIdx.x;
    for (int i = tid; i < NODES * NODES; i += FBLOCK) {
        const int j = i >> 7, k = i & 127;
        sW0T[k * LDS_PITCH + j] = W0[i];
        sW1 [j * LDS_PITCH + k] = W1[i];
    }
    __syncthreads();
    const int n = blockIdx.x * FBLOCK + tid;
    if (n >= npts) return;
    const float px = xs[n*3], py = xs[n*3+1], pz = xs[n*3+2];
    constexpr float INV_SCALE = 1.0f / 1.48f;
    float h[NODES];
    #pragma unroll
    for (int j = 0; j < NODES; ++j) h[j] = b0[j];
    for (int g = 0; g < NG; ++g) {
        const float cx = (px * scales[g*3+0] + trans[g*3+0]) * INV_SCALE;
        const float cy = (py * scales[g*3+1] + trans[g*3+1]) * INV_SCALE;
        const float cz = (pz * scales[g*3+2] + trans[g*3+2]) * INV_SCALE;
        const float fx = (cx + 1.0f) * 31.5f, fy = (cy + 1.0f) * 31.5f, fz = (cz + 1.0f) * 31.5f;
        const float fx0 = floorf(fx), fy0 = floorf(fy), fz0 = floorf(fz);
        const float wx = fx - fx0, wy = fy - fy0, wz = fz - fz0;
        const int x0 = (int)fx0, y0 = (int)fy0, z0 = (int)fz0;
        const int xb = min(max(x0, 0), RES - 2);
        const float wx0 = ((unsigned)x0 < (unsigned)RES) ? (1.0f - wx) : 0.0f;
        const float wx1 = ((unsigned)(x0+1) < (unsigned)RES) ? wx : 0.0f;
        const float wA = (x0 == xb ? wx0 : 0.0f) + (x0 + 1 == xb ? wx1 : 0.0f);
        const float wB = (x0 == xb + 1 ? wx0 : 0.0f) + (x0 == xb ? wx1 : 0.0f);
        const float wy0 = ((unsigned)y0 < (unsigned)RES) ? (1.0f - wy) : 0.0f;
        const float wy1 = ((unsigned)(y0+1) < (unsigned)RES) ? wy : 0.0f;
        const int yc0 = min(max(y0, 0), RES-1), yc1 = min(max(y0+1, 0), RES-1);
        const float wz0 = ((unsigned)z0 < (unsigned)RES) ? (1.0f - wz) : 0.0f;
        const float wz1 = ((unsigned)(z0+1) < (unsigned)RES) ? wz : 0.0f;
        const int zc0 = min(max(z0, 0), RES-1), zc1 = min(max(z0+1, 0), RES-1);
        const float w00 = wz0*wy0, w01 = wz0*wy1, w10 = wz1*wy0, w11 = wz1*wy1;
        const int o00 = (zc0*RES+yc0)*RES+xb, o01 = (zc0*RES+yc1)*RES+xb;
        const int o10 = (zc1*RES+yc0)*RES+xb, o11 = (zc1*RES+yc1)*RES+xb;
        const float* gp = grids + (size_t)g * (2*RES3);
        const float* gq = gp + RES3;
        float f0 = w00*fmaf(wB, gp[o00+1], wA*gp[o00]);
        f0 = fmaf(w01, fmaf(wB, gp[o01+1], wA*gp[o01]), f0);
        f0 = fmaf(w10, fmaf(wB, gp[o10+1], wA*gp[o10]), f0);
        f0 = fmaf(w11, fmaf(wB, gp[o11+1], wA*gp[o11]), f0);
        float f1 = w00*fmaf(wB, gq[o00+1], wA*gq[o00]);
        f1 = fmaf(w01, fmaf(wB, gq[o01+1], wA*gq[o01]), f1);
        f1 = fmaf(w10, fmaf(wB, gq[o10+1], wA*gq[o10]), f1);
        f1 = fmaf(w11, fmaf(wB, gq[o11+1], wA*gq[o11]), f1);
        const float4* rowA = reinterpret_cast<const float4*>(&sW0T[(2*g) * LDS_PITCH]);
        const float4* rowB = reinterpret_cast<const float4*>(&sW0T[(2*g+1) * LDS_PITCH]);
        #pragma unroll
        for (int q = 0; q < NODES/4; ++q) {
            const float4 wa = rowA[q], wb = rowB[q];
            h[4*q+0] = fmaf(f1, wb.x, fmaf(f0, wa.x, h[4*q+0]));
            h[4*q+1] = fmaf(f1, wb.y, fmaf(f0, wa.y, h[4*q+1]));
            h[4*q+2] = fmaf(f1, wb.z, fmaf(f0, wa.z, h[4*q+2]));
            h[4*q+3] = fmaf(f1, wb.w, fmaf(f0, wa.w, h[4*q+3]));
        }
    }
    #pragma unroll
    for (int j = 0; j < NODES; ++j) h[j] = lrelu(h[j]);
    float oacc = b2[0];
    for (int j = 0; j < NODES; ++j) {
        const float4* row = reinterpret_cast<const float4*>(&sW1[j * LDS_PITCH]);
        float a0 = b1[j], a1 = 0.0f, a2 = 0.0f, a3 = 0.0f;
        #pragma unroll
        for (int q = 0; q < NODES/4; ++q) {
            const float4 wv = row[q];
            a0 = fmaf(h[4*q+0], wv.x, a0);
            a1 = fmaf(h[4*q+1], wv.y, a1);
            a2 = fmaf(h[4*q+2], wv.z, a2);
            a3 = fmaf(h[4*q+3], wv.w, a3);
        }
        const float sv = lrelu((a0 + a1) + (a2 + a3));
        oacc = fmaf(sv, W2[j], oacc);
    }
    out[n] = oacc;
}

// ---------------------------------------------------------------- launcher
extern "C" void kernel_launch(void* const* d_in, const int* in_sizes, int n_in,
                              void* d_out, int out_size, void* d_ws, size_t ws_size,
                              hipStream_t stream) {
    const float* xs     = (const float*)d_in[0];
    const float* scales = (const float*)d_in[1];
    const float* trans  = (const float*)d_in[2];
    const float* grids  = (const float*)d_in[3];
    const float* W0     = (const float*)d_in[4];
    const float* b0     = (const float*)d_in[5];
    const float* W1     = (const float*)d_in[6];
    const float* b1     = (const float*)d_in[7];
    const float* W2     = (const float*)d_in[8];
    const float* b2     = (const float*)d_in[9];
    float* out = (float*)d_out;

    const int npts = in_sizes[0] / 3;
    const int npad = (npts + 255) & ~255;
    const int nb   = (npts + 255) / 256;

    auto al = [](size_t v) { return (v + 255) & ~(size_t)255; };
    size_t off = 0;
    const size_t spOff   = off; off += al((size_t)npad * 16);
    const size_t cntOff  = off; off += al((size_t)NBINS * 4);
    const size_t offsOff = off; off += al((size_t)NBINS * 4);
    const size_t wp0Off  = off; off += al((size_t)8192 * 4);
    const size_t wp1Off  = off; off += al((size_t)8192 * 4);
    const size_t b0pOff  = off; off += al(128 * 4);
    const size_t b1pOff  = off; off += al(128 * 4);
    const size_t w2pOff  = off; off += al(128 * 4);
    const size_t cAOff   = off; off += al(64 * 16);
    const size_t cBOff   = off; off += al(64 * 16);
    const size_t needBase = off;
    const size_t gpkOff  = off; off += al((size_t)NG * RES3 * 8);
    const size_t needFull = off;

    if (ws_size < needBase) {
        const int fb = (npts + FBLOCK - 1) / FBLOCK;
        amgsrn_fused<<<fb, FBLOCK, 0, stream>>>(xs, scales, trans, grids,
                                                W0, b0, W1, b1, W2, b2, out, npts);
        return;
    }

    char* ws = (char*)d_ws;
    float4*   sp    = (float4*)(ws + spOff);
    unsigned* cnt   = (unsigned*)(ws + cntOff);
    unsigned* offs  = (unsigned*)(ws + offsOff);
    unsigned* wp0   = (unsigned*)(ws + wp0Off);
    unsigned* wp1   = (unsigned*)(ws + wp1Off);
    float*    b0p   = (float*)(ws + b0pOff);
    float*    b1p   = (float*)(ws + b1pOff);
    float*    w2p   = (float*)(ws + w2pOff);
    float4*   coefA = (float4*)(ws + cAOff);
    float4*   coefB = (float4*)(ws + cBOff);
    float2*   gpk   = (float2*)(ws + gpkOff);
    const bool packed = (ws_size >= needFull);

    zero_k<<<NBINS/256, 256, 0, stream>>>(cnt);
    packw_k<<<33, 256, 0, stream>>>(W0, W1, b0, b1, W2, scales, trans,
                                    wp0, wp1, b0p, b1p, w2p, coefA, coefB);
    if (packed)
        repack_k<<<4096, 256, 0, stream>>>(grids, gpk, NG * RES3);
    hist_k<<<nb, 256, 0, stream>>>(xs, cnt, npts);
    scan_k<<<1, 1024, 0, stream>>>(cnt, offs);
    scatter_k<<<nb, 256, 0, stream>>>(xs, offs, sp, npts);

    const int fb = npad / 256;
    if (packed)
        fused_k<1><<<fb, 256, 0, stream>>>(sp, gpk, grids, coefA, coefB,
                                           (const uint4v*)wp0, (const uint4v*)wp1,
                                           b0p, b1p, w2p, b2, out, npts);
    else
        fused_k<0><<<fb, 256, 0, stream>>>(sp, nullptr, grids, coefA, coefB,
                                           (const uint4v*)wp0, (const uint4v*)wp1,
                                           b0p, b1p, w2p, b2, out, npts);
}